// Round 4
// baseline (212.017 us; speedup 1.0000x reference)
//
#include <hip/hip_runtime.h>
#include <hip/hip_bf16.h>
#include <cmath>

// Problem constants
#define N_TOK 16384   // 4*4096
#define DM    1024
#define CH    256
#define SGRID 16
#define NTP   24      // padded n-tiles (21 real: 16 W1 + 5 score, 3 junk)
// wsB layout (ushort): [((kk*24 + nt)*64 + lane)*8 + j] = bf16(B[k][n])
//   k = kk*32 + (lane>>4)*8 + j, n = nt*16 + (lane&15), kk in [0,32)
// -> each (kk,nt) fragment is 1024 contiguous bytes, lane-ordered.

typedef __attribute__((ext_vector_type(8))) short short8;
typedef __attribute__((ext_vector_type(4))) float floatx4;

__device__ __forceinline__ unsigned short f2bf(float f) {
  union { float f; unsigned int u; } v; v.f = f;
  unsigned int r = v.u + 0x7FFFu + ((v.u >> 16) & 1u);  // RNE
  return (unsigned short)(r >> 16);
}

__device__ __forceinline__ short8 cvt8(float4 u, float4 v) {
  union { short8 s; __hip_bfloat162 h[4]; } r;
  r.h[0] = __float22bfloat162_rn(make_float2(u.x, u.y));
  r.h[1] = __float22bfloat162_rn(make_float2(u.z, u.w));
  r.h[2] = __float22bfloat162_rn(make_float2(v.x, v.y));
  r.h[3] = __float22bfloat162_rn(make_float2(v.z, v.w));
  return r.s;
}

__device__ __forceinline__ float calibrate(float s, const float* __restrict__ kn, float temp_eff) {
  float nrm = 1.0f / (1.0f + expf(-s / temp_eff));
  float idxf = nrm * 7.0f;
  int il = (int)idxf; if (il > 6) il = 6;
  float tt = idxf - (float)il;
  float lo = kn[il], hi = kn[il + 1];
  return lo + tt * (hi - lo);
}

// ---------------- K0: prep swizzled B (grid 32 = one block per kk) ----------------
__global__ __launch_bounds__(256) void prep_kernel(
    const float* __restrict__ sig_raw, const float* __restrict__ w1,
    unsigned short* __restrict__ wsB) {
  __shared__ float Wt[32][260];   // W1 rows kk*32..+31, all 256 cols
  __shared__ float St[64][33];    // ternarized sig, 64 tiles x 32 k
  int kk = blockIdx.x, tid = threadIdx.x;
  {
    int r = tid >> 3, c0 = (tid & 7) * 32;
    const float* src = w1 + (size_t)(kk * 32 + r) * CH + c0;
#pragma unroll
    for (int i = 0; i < 8; ++i)
      *(float4*)(&Wt[r][c0 + 4 * i]) = *(const float4*)(src + 4 * i);
  }
  {
    int t = tid >> 2, c0 = (tid & 3) * 8;
    const float* src = sig_raw + (size_t)t * DM + kk * 32 + c0;
#pragma unroll
    for (int i = 0; i < 8; ++i) {
      float rr = src[i];
      St[t][c0 + i] = (rr > 0.3f) ? 1.f : ((rr < -0.3f) ? -1.f : 0.f);
    }
  }
  __syncthreads();
  // W1 tiles nt=0..15
#pragma unroll
  for (int i = 0; i < 4; ++i) {
    int idx = i * 256 + tid;             // 0..1023 = (nt, lane)
    int nt = idx >> 6, lane = idx & 63;
    int q = lane >> 4, l = lane & 15;
    short8 v;
#pragma unroll
    for (int j = 0; j < 8; ++j) v[j] = (short)f2bf(Wt[q * 8 + j][nt * 16 + l]);
    *(short8*)(wsB + ((size_t)(kk * NTP + nt) * 64 + lane) * 8) = v;
  }
  // sig tiles nt=16..20
#pragma unroll
  for (int i = 0; i < 2; ++i) {
    int idx = i * 256 + tid;
    if (idx < 320) {
      int nt = 16 + (idx >> 6), lane = idx & 63;
      int q = lane >> 4, l = lane & 15;
      int n = nt * 16 + l;
      short8 v;
#pragma unroll
      for (int j = 0; j < 8; ++j) {
        int kl = q * 8 + j;
        float val = 0.f;
        if (n < 264) {
          float s = 0.f;
#pragma unroll
          for (int m = 0; m < 8; ++m) s += St[(n - 256) * 8 + m][kl];
          val = (s > 0.f) ? 1.f : ((s < 0.f) ? -1.f : 0.f);
        } else if (n < 328) {
          val = St[n - 264][kl];
        }
        v[j] = (short)f2bf(val);
      }
      *(short8*)(wsB + ((size_t)(kk * NTP + nt) * 64 + lane) * 8) = v;
    }
  }
}

// ---------------- K1: fused GEMM + routing + spline + residual + LN ----------------
// grid 256 (64 tokens/block), 1024 threads (16 waves). No LDS/barriers in K-loop.
// wave w: m-tile h=w>>2 (rows h*16..h*16+15), n-tiles (w&3)+4s, s=0..5.
#define LOADK(kk, bv, av)                                                   \
  {                                                                         \
    const char* bp = bBase + (size_t)(kk) * (NTP * 1024);                   \
    _Pragma("unroll") for (int s = 0; s < 6; ++s)                           \
        bv[s] = *(const short8*)(bp + s * 4096);                            \
    const float* ap = aBase + (kk) * 32;                                    \
    av[0] = *(const float4*)(ap);                                           \
    av[1] = *(const float4*)(ap + 4);                                       \
  }

#define COMPUTE(bv, av)                                                     \
  {                                                                         \
    short8 aa = cvt8(av[0], av[1]);                                         \
    _Pragma("unroll") for (int s = 0; s < 6; ++s)                           \
      acc[s] = __builtin_amdgcn_mfma_f32_16x16x32_bf16(aa, bv[s], acc[s], 0, 0, 0); \
  }

__global__ __launch_bounds__(1024, 4) void fused_kernel(
    const float* __restrict__ x, const unsigned short* __restrict__ wsB,
    const float* __restrict__ b1, const float* __restrict__ w2,
    const float* __restrict__ b2, const float* __restrict__ knots,
    const float* __restrict__ temperature, const float* __restrict__ sw1,
    const float* __restrict__ sb1, const float* __restrict__ sw2,
    const float* __restrict__ sb2, const float* __restrict__ dirs,
    const float* __restrict__ gma, const float* __restrict__ bta,
    const float* __restrict__ oscale, float* __restrict__ out) {
  __shared__ float Ssc[64][81];       // scores: [token][sc] 0..7=cluster, 8..71=tile
  __shared__ float Psh[4][4][16][2];  // comp partials [h][w3][row16][c]
  __shared__ float ScaleS[64];
  __shared__ int   TidxS[64];

  int tid = threadIdx.x;
  int wave = tid >> 6, lane = tid & 63, quad = lane >> 4, l15 = lane & 15;
  int w3 = wave & 3, h = wave >> 2;
  int m0 = blockIdx.x * 64;

  floatx4 acc[6];
#pragma unroll
  for (int s = 0; s < 6; ++s) acc[s] = (floatx4){0.f, 0.f, 0.f, 0.f};

  const char* bBase = (const char*)wsB + w3 * 1024 + lane * 16;
  const float* aBase = x + (size_t)(m0 + h * 16 + l15) * DM + quad * 8;

  short8 bA[6], bB_[6];
  float4 aA[2], aB_[2];
  LOADK(0, bA, aA);
#pragma unroll 1
  for (int kk = 0; kk < 30; kk += 2) {
    LOADK(kk + 1, bB_, aB_);
    COMPUTE(bA, aA);
    LOADK(kk + 2, bA, aA);
    COMPUTE(bB_, aB_);
  }
  LOADK(31, bB_, aB_);
  COMPUTE(bA, aA);
  COMPUTE(bB_, aB_);

  // ---- scores -> LDS (s=4 all waves; s=5 only w3==0 -> sc 64..79) ----
#pragma unroll
  for (int r = 0; r < 4; ++r) {
    int row = h * 16 + quad * 4 + r;
    Ssc[row][w3 * 16 + l15] = acc[4][r];
    if (w3 == 0) Ssc[row][64 + l15] = acc[5][r];
  }

  // ---- comp partials over this wave's 4 W1 tiles (s=0..3) ----
  float p0[4] = {0.f, 0.f, 0.f, 0.f}, p1[4] = {0.f, 0.f, 0.f, 0.f};
#pragma unroll
  for (int s = 0; s < 4; ++s) {
    int col = (w3 + 4 * s) * 16 + l15;
    float b1c = b1[col], w20 = w2[2 * col], w21 = w2[2 * col + 1];
#pragma unroll
    for (int r = 0; r < 4; ++r) {
      float hh = acc[s][r] + b1c;
      hh = 0.5f * hh * (1.0f + erff(hh * 0.7071067811865475f));
      p0[r] += hh * w20;
      p1[r] += hh * w21;
    }
  }
#pragma unroll
  for (int m = 1; m < 16; m <<= 1)
#pragma unroll
    for (int r = 0; r < 4; ++r) {
      p0[r] += __shfl_xor(p0[r], m);
      p1[r] += __shfl_xor(p1[r], m);
    }
  if (l15 == 0) {
#pragma unroll
    for (int r = 0; r < 4; ++r) {
      Psh[h][w3][quad * 4 + r][0] = p0[r];
      Psh[h][w3][quad * 4 + r][1] = p1[r];
    }
  }
  __syncthreads();

  // ---- per-token: comp combine + routing + spline ----
  if (tid < 64) {
    int row = tid, h2 = row >> 4, r16 = row & 15;
    float s0 = b2[0], s1 = b2[1];
#pragma unroll
    for (int j = 0; j < 4; ++j) {
      s0 += Psh[h2][j][r16][0];
      s1 += Psh[h2][j][r16][1];
    }
    float c0 = tanhf(s0), c1 = tanhf(s1);

    float temp_eff = temperature[0] + 1e-6f;
    int cid = 0; float best = -1e30f;
#pragma unroll
    for (int c = 0; c < 8; ++c) {
      float g = calibrate(Ssc[row][c], knots, temp_eff);
      if (g > best) { best = g; cid = c; }
    }
    int lidx = 0; best = -1e30f;
#pragma unroll
    for (int j = 0; j < 8; ++j) {
      float g = calibrate(Ssc[row][8 + cid * 8 + j], knots, temp_eff);
      if (g > best) { best = g; lidx = j; }
    }
    int t = cid * 8 + lidx;

    float mag = sb2[t];
#pragma unroll
    for (int g2 = 0; g2 < SGRID; ++g2) {
      float hv = c0 * sw1[t * 32 + g2] + c1 * sw1[t * 32 + 16 + g2] + sb1[t * 16 + g2];
      hv = fmaxf(hv, 0.f);
      mag += hv * sw2[t * 16 + g2];
    }
    ScaleS[row] = mag * oscale[0];
    TidxS[row] = t;
  }
  __syncthreads();

  // ---- residual + LayerNorm: wave w -> rows w*4 .. w*4+3 ----
  float4 g4[4], be4[4];
#pragma unroll
  for (int i = 0; i < 4; ++i) {
    g4[i] = *(const float4*)(gma + 4 * lane + 256 * i);
    be4[i] = *(const float4*)(bta + 4 * lane + 256 * i);
  }
#pragma unroll 1
  for (int rr = 0; rr < 4; ++rr) {
    int row = wave * 4 + rr;
    float scale = ScaleS[row];
    const float* xr = x + (size_t)(m0 + row) * DM;
    const float* dr = dirs + (size_t)TidxS[row] * DM;
    float4 fv[4];
    float ssum = 0.f, ssq = 0.f;
#pragma unroll
    for (int i = 0; i < 4; ++i) {
      float4 xv = *(const float4*)(xr + 4 * lane + 256 * i);
      float4 d4 = *(const float4*)(dr + 4 * lane + 256 * i);
      fv[i].x = xv.x + scale * d4.x;
      fv[i].y = xv.y + scale * d4.y;
      fv[i].z = xv.z + scale * d4.z;
      fv[i].w = xv.w + scale * d4.w;
      ssum += fv[i].x + fv[i].y + fv[i].z + fv[i].w;
      ssq += fv[i].x * fv[i].x + fv[i].y * fv[i].y + fv[i].z * fv[i].z + fv[i].w * fv[i].w;
    }
#pragma unroll
    for (int m = 1; m < 64; m <<= 1) {
      ssum += __shfl_xor(ssum, m);
      ssq += __shfl_xor(ssq, m);
    }
    float mu = ssum * (1.0f / 1024.0f);
    float var = ssq * (1.0f / 1024.0f) - mu * mu;
    float inv = rsqrtf(var + 1e-5f);
    float* orow = out + (size_t)(m0 + row) * DM;
#pragma unroll
    for (int i = 0; i < 4; ++i) {
      float4 o;
      o.x = (fv[i].x - mu) * inv * g4[i].x + be4[i].x;
      o.y = (fv[i].y - mu) * inv * g4[i].y + be4[i].y;
      o.z = (fv[i].z - mu) * inv * g4[i].z + be4[i].z;
      o.w = (fv[i].w - mu) * inv * g4[i].w + be4[i].w;
      *(float4*)(orow + 4 * lane + 256 * i) = o;
    }
  }
}

extern "C" void kernel_launch(void* const* d_in, const int* in_sizes, int n_in,
                              void* d_out, int out_size, void* d_ws, size_t ws_size,
                              hipStream_t stream) {
  const float* x      = (const float*)d_in[0];
  const float* sigraw = (const float*)d_in[1];
  const float* knots  = (const float*)d_in[2];
  const float* temp   = (const float*)d_in[3];
  const float* cw1    = (const float*)d_in[4];
  const float* cb1    = (const float*)d_in[5];
  const float* cw2    = (const float*)d_in[6];
  const float* cb2    = (const float*)d_in[7];
  const float* sw1    = (const float*)d_in[8];
  const float* sb1    = (const float*)d_in[9];
  const float* sw2    = (const float*)d_in[10];
  const float* sb2    = (const float*)d_in[11];
  const float* dirs   = (const float*)d_in[12];
  const float* gma    = (const float*)d_in[13];
  const float* bta    = (const float*)d_in[14];
  const float* oscale = (const float*)d_in[15];
  float* out = (float*)d_out;

  unsigned short* wsB = (unsigned short*)d_ws;   // 32*24*64*8 ushort = 1,572,864 B

  hipLaunchKernelGGL(prep_kernel, dim3(32), dim3(256), 0, stream,
                     sigraw, cw1, wsB);
  hipLaunchKernelGGL(fused_kernel, dim3(N_TOK / 64), dim3(1024), 0, stream,
                     x, wsB, cb1, cw2, cb2, knots, temp,
                     sw1, sb1, sw2, sb2, dirs, gma, bta, oscale, out);
}

// Round 5
// 196.741 us; speedup vs baseline: 1.0776x; 1.0776x over previous
//
#include <hip/hip_runtime.h>
#include <hip/hip_bf16.h>
#include <cmath>

// Problem constants
#define N_TOK 16384   // 4*4096
#define DM    1024
#define CH    256
#define SGRID 16
#define NTP   24      // padded n-tiles in ws (21 real: 16 W1 + 5 score)
// wsB layout (ushort): [((kk*24 + nt)*64 + lane)*8 + j] = bf16(B[k][n])
//   k = kk*32 + (lane>>4)*8 + j, n = nt*16 + (lane&15), kk in [0,32)
// -> each (kk,nt) fragment is 1024 contiguous bytes, lane-ordered.

typedef __attribute__((ext_vector_type(8))) short short8;
typedef __attribute__((ext_vector_type(4))) float floatx4;

__device__ __forceinline__ unsigned short f2bf(float f) {
  union { float f; unsigned int u; } v; v.f = f;
  unsigned int r = v.u + 0x7FFFu + ((v.u >> 16) & 1u);  // RNE
  return (unsigned short)(r >> 16);
}

__device__ __forceinline__ short8 cvt8(float4 u, float4 v) {
  union { short8 s; __hip_bfloat162 h[4]; } r;
  r.h[0] = __float22bfloat162_rn(make_float2(u.x, u.y));
  r.h[1] = __float22bfloat162_rn(make_float2(u.z, u.w));
  r.h[2] = __float22bfloat162_rn(make_float2(v.x, v.y));
  r.h[3] = __float22bfloat162_rn(make_float2(v.z, v.w));
  return r.s;
}

__device__ __forceinline__ float calibrate(float s, const float* __restrict__ kn, float temp_eff) {
  float nrm = 1.0f / (1.0f + expf(-s / temp_eff));
  float idxf = nrm * 7.0f;
  int il = (int)idxf; if (il > 6) il = 6;
  float tt = idxf - (float)il;
  float lo = kn[il], hi = kn[il + 1];
  return lo + tt * (hi - lo);
}

// ---------------- K0: prep swizzled B (grid 32 = one block per kk) ----------------
__global__ __launch_bounds__(256) void prep_kernel(
    const float* __restrict__ sig_raw, const float* __restrict__ w1,
    unsigned short* __restrict__ wsB) {
  __shared__ float Wt[32][260];   // W1 rows kk*32..+31, all 256 cols
  __shared__ float St[64][33];    // ternarized sig, 64 tiles x 32 k
  int kk = blockIdx.x, tid = threadIdx.x;
  {
    int r = tid >> 3, c0 = (tid & 7) * 32;
    const float* src = w1 + (size_t)(kk * 32 + r) * CH + c0;
#pragma unroll
    for (int i = 0; i < 8; ++i)
      *(float4*)(&Wt[r][c0 + 4 * i]) = *(const float4*)(src + 4 * i);
  }
  {
    int t = tid >> 2, c0 = (tid & 3) * 8;
    const float* src = sig_raw + (size_t)t * DM + kk * 32 + c0;
#pragma unroll
    for (int i = 0; i < 8; ++i) {
      float rr = src[i];
      St[t][c0 + i] = (rr > 0.3f) ? 1.f : ((rr < -0.3f) ? -1.f : 0.f);
    }
  }
  __syncthreads();
  // W1 tiles nt=0..15
#pragma unroll
  for (int i = 0; i < 4; ++i) {
    int idx = i * 256 + tid;             // 0..1023 = (nt, lane)
    int nt = idx >> 6, lane = idx & 63;
    int q = lane >> 4, l = lane & 15;
    short8 v;
#pragma unroll
    for (int j = 0; j < 8; ++j) v[j] = (short)f2bf(Wt[q * 8 + j][nt * 16 + l]);
    *(short8*)(wsB + ((size_t)(kk * NTP + nt) * 64 + lane) * 8) = v;
  }
  // sig tiles nt=16..20
#pragma unroll
  for (int i = 0; i < 2; ++i) {
    int idx = i * 256 + tid;
    if (idx < 320) {
      int nt = 16 + (idx >> 6), lane = idx & 63;
      int q = lane >> 4, l = lane & 15;
      int n = nt * 16 + l;
      short8 v;
#pragma unroll
      for (int j = 0; j < 8; ++j) {
        int kl = q * 8 + j;
        float val = 0.f;
        if (n < 264) {
          float s = 0.f;
#pragma unroll
          for (int m = 0; m < 8; ++m) s += St[(n - 256) * 8 + m][kl];
          val = (s > 0.f) ? 1.f : ((s < 0.f) ? -1.f : 0.f);
        } else if (n < 328) {
          val = St[n - 264][kl];
        }
        v[j] = (short)f2bf(val);
      }
      *(short8*)(wsB + ((size_t)(kk * NTP + nt) * 64 + lane) * 8) = v;
    }
  }
}

// ---------------- K1: fused GEMM + routing + spline + residual + LN ----------------
// grid 512 (32 tokens/block), 512 threads (8 waves), 2 blocks/CU.
// wave w: m-tile h=w>>2, n-tiles (w&3)+4s, s=0..5 (s=5 only for w3==0).
// B staged to LDS via global_load_lds DMA, double-buffered, 1 barrier/kk.

#define DMAB(kk, buf)                                                       \
  {                                                                         \
    const char* g = gB + (size_t)(kk) * (NTP * 1024);                       \
    _Pragma("unroll") for (int i = 0; i < 3; ++i) {                         \
      int c = i * 8 + wave;                                                 \
      if (c < 21)                                                           \
        __builtin_amdgcn_global_load_lds(                                   \
            (const __attribute__((address_space(1))) void*)(g + c * 1024 + lane * 16), \
            (__attribute__((address_space(3))) void*)((buf) + c * 1024), 16, 0, 0); \
    }                                                                       \
  }

#define LOADA(kk, av)                                                       \
  {                                                                         \
    const float* ap = aBase + (kk) * 32;                                    \
    av[0] = *(const float4*)(ap);                                           \
    av[1] = *(const float4*)(ap + 4);                                       \
  }

#define COMPUTE(buf, av)                                                    \
  {                                                                         \
    short8 aa = cvt8(av[0], av[1]);                                         \
    _Pragma("unroll") for (int s = 0; s < 5; ++s) {                         \
      short8 b = *(const short8*)((buf) + (w3 + 4 * s) * 1024 + lane * 16); \
      acc[s] = __builtin_amdgcn_mfma_f32_16x16x32_bf16(aa, b, acc[s], 0, 0, 0); \
    }                                                                       \
    if (w3 == 0) {                                                          \
      short8 b = *(const short8*)((buf) + 20 * 1024 + lane * 16);           \
      acc[5] = __builtin_amdgcn_mfma_f32_16x16x32_bf16(aa, b, acc[5], 0, 0, 0); \
    }                                                                       \
  }

__global__ __launch_bounds__(512, 4) void fused_kernel(
    const float* __restrict__ x, const unsigned short* __restrict__ wsB,
    const float* __restrict__ b1, const float* __restrict__ w2,
    const float* __restrict__ b2, const float* __restrict__ knots,
    const float* __restrict__ temperature, const float* __restrict__ sw1,
    const float* __restrict__ sb1, const float* __restrict__ sw2,
    const float* __restrict__ sb2, const float* __restrict__ dirs,
    const float* __restrict__ gma, const float* __restrict__ bta,
    const float* __restrict__ oscale, float* __restrict__ out) {
  __shared__ char BshRaw[2 * 21504];   // two B buffers, 21 KB each
  __shared__ float Ssc[32][81];        // scores: 0..7=cluster, 8..71=tile
  __shared__ float Psh[2][4][16][2];   // comp partials [h][w3][row16][c]
  __shared__ float ScaleS[32];
  __shared__ int   TidxS[32];

  int tid = threadIdx.x;
  int wave = tid >> 6, lane = tid & 63, quad = lane >> 4, l15 = lane & 15;
  int w3 = wave & 3, h = wave >> 2;
  int m0 = blockIdx.x * 32;

  floatx4 acc[6];
#pragma unroll
  for (int s = 0; s < 6; ++s) acc[s] = (floatx4){0.f, 0.f, 0.f, 0.f};

  const char* gB = (const char*)wsB;
  const float* aBase = x + (size_t)(m0 + h * 16 + l15) * DM + quad * 8;
  char* buf0 = BshRaw;
  char* buf1 = BshRaw + 21504;

  float4 aA[2], aB_[2];
  DMAB(0, buf0);
  LOADA(0, aA);
#pragma unroll 1
  for (int kk = 0; kk < 32; kk += 2) {
    __syncthreads();                       // DMA for buf0 done; buf1 reads done
    if (kk + 1 < 32) { DMAB(kk + 1, buf1); LOADA(kk + 1, aB_); }
    COMPUTE(buf0, aA);
    __syncthreads();                       // DMA for buf1 done; buf0 reads done
    if (kk + 2 < 32) { DMAB(kk + 2, buf0); LOADA(kk + 2, aA); }
    COMPUTE(buf1, aB_);
  }

  // ---- scores -> LDS (s=4 all waves; s=5 only w3==0 -> sc 64..79) ----
#pragma unroll
  for (int r = 0; r < 4; ++r) {
    int row = h * 16 + quad * 4 + r;
    Ssc[row][w3 * 16 + l15] = acc[4][r];
    if (w3 == 0) Ssc[row][64 + l15] = acc[5][r];
  }

  // ---- comp partials over this wave's 4 W1 tiles (s=0..3) ----
  float p0[4] = {0.f, 0.f, 0.f, 0.f}, p1[4] = {0.f, 0.f, 0.f, 0.f};
#pragma unroll
  for (int s = 0; s < 4; ++s) {
    int col = (w3 + 4 * s) * 16 + l15;
    float b1c = b1[col], w20 = w2[2 * col], w21 = w2[2 * col + 1];
#pragma unroll
    for (int r = 0; r < 4; ++r) {
      float hh = acc[s][r] + b1c;
      hh = 0.5f * hh * (1.0f + erff(hh * 0.7071067811865475f));
      p0[r] += hh * w20;
      p1[r] += hh * w21;
    }
  }
#pragma unroll
  for (int m = 1; m < 16; m <<= 1)
#pragma unroll
    for (int r = 0; r < 4; ++r) {
      p0[r] += __shfl_xor(p0[r], m);
      p1[r] += __shfl_xor(p1[r], m);
    }
  if (l15 == 0) {
#pragma unroll
    for (int r = 0; r < 4; ++r) {
      Psh[h][w3][quad * 4 + r][0] = p0[r];
      Psh[h][w3][quad * 4 + r][1] = p1[r];
    }
  }
  __syncthreads();

  // ---- per-token: comp combine + routing + spline ----
  if (tid < 32) {
    int row = tid, h2 = row >> 4, r16 = row & 15;
    float s0 = b2[0], s1 = b2[1];
#pragma unroll
    for (int j = 0; j < 4; ++j) {
      s0 += Psh[h2][j][r16][0];
      s1 += Psh[h2][j][r16][1];
    }
    float c0 = tanhf(s0), c1 = tanhf(s1);

    float temp_eff = temperature[0] + 1e-6f;
    int cid = 0; float best = -1e30f;
#pragma unroll
    for (int c = 0; c < 8; ++c) {
      float g = calibrate(Ssc[row][c], knots, temp_eff);
      if (g > best) { best = g; cid = c; }
    }
    int lidx = 0; best = -1e30f;
#pragma unroll
    for (int j = 0; j < 8; ++j) {
      float g = calibrate(Ssc[row][8 + cid * 8 + j], knots, temp_eff);
      if (g > best) { best = g; lidx = j; }
    }
    int t = cid * 8 + lidx;

    float mag = sb2[t];
#pragma unroll
    for (int g2 = 0; g2 < SGRID; ++g2) {
      float hv = c0 * sw1[t * 32 + g2] + c1 * sw1[t * 32 + 16 + g2] + sb1[t * 16 + g2];
      hv = fmaxf(hv, 0.f);
      mag += hv * sw2[t * 16 + g2];
    }
    ScaleS[row] = mag * oscale[0];
    TidxS[row] = t;
  }
  __syncthreads();

  // ---- residual + LayerNorm: wave w -> rows w*4 .. w*4+3 ----
  float4 g4[4], be4[4];
#pragma unroll
  for (int i = 0; i < 4; ++i) {
    g4[i] = *(const float4*)(gma + 4 * lane + 256 * i);
    be4[i] = *(const float4*)(bta + 4 * lane + 256 * i);
  }
#pragma unroll 1
  for (int rr = 0; rr < 4; ++rr) {
    int row = wave * 4 + rr;
    float scale = ScaleS[row];
    const float* xr = x + (size_t)(m0 + row) * DM;
    const float* dr = dirs + (size_t)TidxS[row] * DM;
    float4 fv[4];
    float ssum = 0.f, ssq = 0.f;
#pragma unroll
    for (int i = 0; i < 4; ++i) {
      float4 xv = *(const float4*)(xr + 4 * lane + 256 * i);
      float4 d4 = *(const float4*)(dr + 4 * lane + 256 * i);
      fv[i].x = xv.x + scale * d4.x;
      fv[i].y = xv.y + scale * d4.y;
      fv[i].z = xv.z + scale * d4.z;
      fv[i].w = xv.w + scale * d4.w;
      ssum += fv[i].x + fv[i].y + fv[i].z + fv[i].w;
      ssq += fv[i].x * fv[i].x + fv[i].y * fv[i].y + fv[i].z * fv[i].z + fv[i].w * fv[i].w;
    }
#pragma unroll
    for (int m = 1; m < 64; m <<= 1) {
      ssum += __shfl_xor(ssum, m);
      ssq += __shfl_xor(ssq, m);
    }
    float mu = ssum * (1.0f / 1024.0f);
    float var = ssq * (1.0f / 1024.0f) - mu * mu;
    float inv = rsqrtf(var + 1e-5f);
    float* orow = out + (size_t)(m0 + row) * DM;
#pragma unroll
    for (int i = 0; i < 4; ++i) {
      float4 o;
      o.x = (fv[i].x - mu) * inv * g4[i].x + be4[i].x;
      o.y = (fv[i].y - mu) * inv * g4[i].y + be4[i].y;
      o.z = (fv[i].z - mu) * inv * g4[i].z + be4[i].z;
      o.w = (fv[i].w - mu) * inv * g4[i].w + be4[i].w;
      *(float4*)(orow + 4 * lane + 256 * i) = o;
    }
  }
}

extern "C" void kernel_launch(void* const* d_in, const int* in_sizes, int n_in,
                              void* d_out, int out_size, void* d_ws, size_t ws_size,
                              hipStream_t stream) {
  const float* x      = (const float*)d_in[0];
  const float* sigraw = (const float*)d_in[1];
  const float* knots  = (const float*)d_in[2];
  const float* temp   = (const float*)d_in[3];
  const float* cw1    = (const float*)d_in[4];
  const float* cb1    = (const float*)d_in[5];
  const float* cw2    = (const float*)d_in[6];
  const float* cb2    = (const float*)d_in[7];
  const float* sw1    = (const float*)d_in[8];
  const float* sb1    = (const float*)d_in[9];
  const float* sw2    = (const float*)d_in[10];
  const float* sb2    = (const float*)d_in[11];
  const float* dirs   = (const float*)d_in[12];
  const float* gma    = (const float*)d_in[13];
  const float* bta    = (const float*)d_in[14];
  const float* oscale = (const float*)d_in[15];
  float* out = (float*)d_out;

  unsigned short* wsB = (unsigned short*)d_ws;   // 32*24*64*8 ushort = 1,572,864 B

  hipLaunchKernelGGL(prep_kernel, dim3(32), dim3(256), 0, stream,
                     sigraw, cw1, wsB);
  hipLaunchKernelGGL(fused_kernel, dim3(N_TOK / 32), dim3(512), 0, stream,
                     x, wsB, cb1, cw2, cb2, knots, temp,
                     sw1, sb1, sw2, sb2, dirs, gma, bta, oscale, out);
}

// Round 6
// 184.218 us; speedup vs baseline: 1.1509x; 1.0680x over previous
//
#include <hip/hip_runtime.h>
#include <hip/hip_bf16.h>
#include <cmath>

// Problem constants
#define N_TOK 16384   // 4*4096
#define DM    1024
#define CH    256
#define SGRID 16
#define NTP   24      // padded n-tiles in ws (21 real: 16 W1 + 5 score)
// wsB layout (ushort): [((kk*24 + nt)*64 + lane)*8 + j] = bf16(B[k][n])
//   k = kk*32 + (lane>>4)*8 + j, n = nt*16 + (lane&15), kk in [0,32)

typedef __attribute__((ext_vector_type(8))) short short8;
typedef __attribute__((ext_vector_type(4))) float floatx4;

__device__ __forceinline__ unsigned short f2bf(float f) {
  union { float f; unsigned int u; } v; v.f = f;
  unsigned int r = v.u + 0x7FFFu + ((v.u >> 16) & 1u);  // RNE
  return (unsigned short)(r >> 16);
}

__device__ __forceinline__ short8 cvt8(float4 u, float4 v) {
  union { short8 s; __hip_bfloat162 h[4]; } r;
  r.h[0] = __float22bfloat162_rn(make_float2(u.x, u.y));
  r.h[1] = __float22bfloat162_rn(make_float2(u.z, u.w));
  r.h[2] = __float22bfloat162_rn(make_float2(v.x, v.y));
  r.h[3] = __float22bfloat162_rn(make_float2(v.z, v.w));
  return r.s;
}

__device__ __forceinline__ float bf2f(unsigned short b) {
  union { unsigned int u; float f; } v; v.u = ((unsigned int)b) << 16; return v.f;
}

__device__ __forceinline__ float calibrate(float s, const float* __restrict__ kn, float temp_eff) {
  float nrm = 1.0f / (1.0f + expf(-s / temp_eff));
  float idxf = nrm * 7.0f;
  int il = (int)idxf; if (il > 6) il = 6;
  float tt = idxf - (float)il;
  float lo = kn[il], hi = kn[il + 1];
  return lo + tt * (hi - lo);
}

// ---------------- K0: prep swizzled B (grid 32 = one block per kk) ----------------
__global__ __launch_bounds__(256) void prep_kernel(
    const float* __restrict__ sig_raw, const float* __restrict__ w1,
    unsigned short* __restrict__ wsB) {
  __shared__ float Wt[32][260];
  __shared__ float St[64][33];
  int kk = blockIdx.x, tid = threadIdx.x;
  {
    int r = tid >> 3, c0 = (tid & 7) * 32;
    const float* src = w1 + (size_t)(kk * 32 + r) * CH + c0;
#pragma unroll
    for (int i = 0; i < 8; ++i)
      *(float4*)(&Wt[r][c0 + 4 * i]) = *(const float4*)(src + 4 * i);
  }
  {
    int t = tid >> 2, c0 = (tid & 3) * 8;
    const float* src = sig_raw + (size_t)t * DM + kk * 32 + c0;
#pragma unroll
    for (int i = 0; i < 8; ++i) {
      float rr = src[i];
      St[t][c0 + i] = (rr > 0.3f) ? 1.f : ((rr < -0.3f) ? -1.f : 0.f);
    }
  }
  __syncthreads();
#pragma unroll
  for (int i = 0; i < 4; ++i) {
    int idx = i * 256 + tid;
    int nt = idx >> 6, lane = idx & 63;
    int q = lane >> 4, l = lane & 15;
    short8 v;
#pragma unroll
    for (int j = 0; j < 8; ++j) v[j] = (short)f2bf(Wt[q * 8 + j][nt * 16 + l]);
    *(short8*)(wsB + ((size_t)(kk * NTP + nt) * 64 + lane) * 8) = v;
  }
#pragma unroll
  for (int i = 0; i < 2; ++i) {
    int idx = i * 256 + tid;
    if (idx < 320) {
      int nt = 16 + (idx >> 6), lane = idx & 63;
      int q = lane >> 4, l = lane & 15;
      int n = nt * 16 + l;
      short8 v;
#pragma unroll
      for (int j = 0; j < 8; ++j) {
        int kl = q * 8 + j;
        float val = 0.f;
        if (n < 264) {
          float s = 0.f;
#pragma unroll
          for (int m = 0; m < 8; ++m) s += St[(n - 256) * 8 + m][kl];
          val = (s > 0.f) ? 1.f : ((s < 0.f) ? -1.f : 0.f);
        } else if (n < 328) {
          val = St[n - 264][kl];
        }
        v[j] = (short)f2bf(val);
      }
      *(short8*)(wsB + ((size_t)(kk * NTP + nt) * 64 + lane) * 8) = v;
    }
  }
}

// ---------------- K1: fused GEMM + routing + spline + residual + LN ----------------
// grid 512 (32 tokens/block), 512 threads (8 waves), 2 blocks/CU.
// x staged ONCE to LDS (bf16, XOR-swizzled 16B chunks); K-loop barrier-free:
// A from LDS, B register ping-pong from L2-resident wsB.
// wave w: m-tile h=w>>2, n-tiles (w&3)+4s, s=0..5 (s=5 only w3==0).

#define LOADK(kk, bv, aav)                                                  \
  {                                                                         \
    const char* bp = bBase + (size_t)(kk) * (NTP * 1024);                   \
    _Pragma("unroll") for (int s = 0; s < 5; ++s)                           \
        bv[s] = *(const short8*)(bp + s * 4096);                            \
    if (w3 == 0) bv[5] = *(const short8*)(bp + 20 * 1024);                  \
    aav = *(const short8*)(Xsh + arow + (((unsigned)((kk) * 4 + quad) ^ sw) << 3)); \
  }

#define COMPUTE(bv, aav)                                                    \
  {                                                                         \
    _Pragma("unroll") for (int s = 0; s < 5; ++s)                           \
      acc[s] = __builtin_amdgcn_mfma_f32_16x16x32_bf16(aav, bv[s], acc[s], 0, 0, 0); \
    if (w3 == 0)                                                            \
      acc[5] = __builtin_amdgcn_mfma_f32_16x16x32_bf16(aav, bv[5], acc[5], 0, 0, 0); \
  }

__global__ __launch_bounds__(512, 4) void fused_kernel(
    const float* __restrict__ x, const unsigned short* __restrict__ wsB,
    const float* __restrict__ b1, const float* __restrict__ w2,
    const float* __restrict__ b2, const float* __restrict__ knots,
    const float* __restrict__ temperature, const float* __restrict__ sw1,
    const float* __restrict__ sb1, const float* __restrict__ sw2,
    const float* __restrict__ sb2, const float* __restrict__ dirs,
    const float* __restrict__ gma, const float* __restrict__ bta,
    const float* __restrict__ oscale, float* __restrict__ out) {
  __shared__ unsigned short Xsh[32 * 1024];   // 64 KB: row*1024 + (chunk^(row&7))*8
  __shared__ float Ssc[32][73];               // scores: 0..7 cluster, 8..71 tile
  __shared__ float Psh[2][4][16][2];
  __shared__ float ScaleS[32];
  __shared__ int   TidxS[32];

  int tid = threadIdx.x;
  int wave = tid >> 6, lane = tid & 63, quad = lane >> 4, l15 = lane & 15;
  int w3 = wave & 3, h = wave >> 2;
  int m0 = blockIdx.x * 32;

  // ---- stage x -> Xsh (bf16, swizzled), fully coalesced ----
  {
    const float* base = x + (size_t)m0 * DM;
#pragma unroll
    for (int i2 = 0; i2 < 8; ++i2) {
      int cg = tid + 512 * i2;                // global chunk 0..4095
      float4 p = *(const float4*)(base + cg * 8);
      float4 q = *(const float4*)(base + cg * 8 + 4);
      int row = cg >> 7, cir = cg & 127;
      int pos = cir ^ (row & 7);
      *(short8*)(Xsh + row * 1024 + pos * 8) = cvt8(p, q);
    }
  }
  __syncthreads();

  floatx4 acc[6];
#pragma unroll
  for (int s = 0; s < 6; ++s) acc[s] = (floatx4){0.f, 0.f, 0.f, 0.f};

  const char* bBase = (const char*)wsB + w3 * 1024 + lane * 16;
  int arow = (h * 16 + l15) * 1024;
  unsigned sw = (unsigned)(l15 & 7);

  short8 bA[6], bB_[6], aA, aB_;
  LOADK(0, bA, aA);
#pragma unroll 1
  for (int kk = 0; kk < 30; kk += 2) {
    LOADK(kk + 1, bB_, aB_);
    COMPUTE(bA, aA);
    LOADK(kk + 2, bA, aA);
    COMPUTE(bB_, aB_);
  }
  LOADK(31, bB_, aB_);
  COMPUTE(bA, aA);
  COMPUTE(bB_, aB_);

  // ---- scores -> LDS ----
#pragma unroll
  for (int r = 0; r < 4; ++r) {
    int row = h * 16 + quad * 4 + r;
    Ssc[row][w3 * 16 + l15] = acc[4][r];
    if (w3 == 0 && l15 < 8) Ssc[row][64 + l15] = acc[5][r];
  }

  // ---- comp partials over this wave's 4 W1 tiles (s=0..3) ----
  float p0[4] = {0.f, 0.f, 0.f, 0.f}, p1[4] = {0.f, 0.f, 0.f, 0.f};
#pragma unroll
  for (int s = 0; s < 4; ++s) {
    int col = (w3 + 4 * s) * 16 + l15;
    float b1c = b1[col], w20 = w2[2 * col], w21 = w2[2 * col + 1];
#pragma unroll
    for (int r = 0; r < 4; ++r) {
      float hh = acc[s][r] + b1c;
      hh = 0.5f * hh * (1.0f + erff(hh * 0.7071067811865475f));
      p0[r] += hh * w20;
      p1[r] += hh * w21;
    }
  }
#pragma unroll
  for (int m = 1; m < 16; m <<= 1)
#pragma unroll
    for (int r = 0; r < 4; ++r) {
      p0[r] += __shfl_xor(p0[r], m);
      p1[r] += __shfl_xor(p1[r], m);
    }
  if (l15 == 0) {
#pragma unroll
    for (int r = 0; r < 4; ++r) {
      Psh[h][w3][quad * 4 + r][0] = p0[r];
      Psh[h][w3][quad * 4 + r][1] = p1[r];
    }
  }
  __syncthreads();

  // ---- per-token: comp combine + routing + spline ----
  if (tid < 32) {
    int row = tid, h2 = row >> 4, r16 = row & 15;
    float s0 = b2[0], s1 = b2[1];
#pragma unroll
    for (int j = 0; j < 4; ++j) {
      s0 += Psh[h2][j][r16][0];
      s1 += Psh[h2][j][r16][1];
    }
    float c0 = tanhf(s0), c1 = tanhf(s1);

    float temp_eff = temperature[0] + 1e-6f;
    int cid = 0; float best = -1e30f;
#pragma unroll
    for (int c = 0; c < 8; ++c) {
      float g = calibrate(Ssc[row][c], knots, temp_eff);
      if (g > best) { best = g; cid = c; }
    }
    int lidx = 0; best = -1e30f;
#pragma unroll
    for (int j = 0; j < 8; ++j) {
      float g = calibrate(Ssc[row][8 + cid * 8 + j], knots, temp_eff);
      if (g > best) { best = g; lidx = j; }
    }
    int t = cid * 8 + lidx;

    float mag = sb2[t];
#pragma unroll
    for (int g2 = 0; g2 < SGRID; ++g2) {
      float hv = c0 * sw1[t * 32 + g2] + c1 * sw1[t * 32 + 16 + g2] + sb1[t * 16 + g2];
      hv = fmaxf(hv, 0.f);
      mag += hv * sw2[t * 16 + g2];
    }
    ScaleS[row] = mag * oscale[0];
    TidxS[row] = t;
  }
  __syncthreads();

  // ---- residual + LN: wave w -> rows w*4..w*4+3; x from Xsh (bf16) ----
#pragma unroll 1
  for (int rr = 0; rr < 4; ++rr) {
    int row = wave * 4 + rr;
    int r7 = row & 7;
    float scale = ScaleS[row];
    const float* dr = dirs + (size_t)TidxS[row] * DM + lane * 16;
    const unsigned short* xrow = Xsh + row * 1024;
    short8 h0 = *(const short8*)(xrow + (unsigned)((2 * lane) ^ r7) * 8);
    short8 h1 = *(const short8*)(xrow + (unsigned)((2 * lane + 1) ^ r7) * 8);
    float fv[16];
    float ssum = 0.f, ssq = 0.f;
#pragma unroll
    for (int i = 0; i < 4; ++i) {
      float4 d4 = *(const float4*)(dr + 4 * i);
      float xa = bf2f((unsigned short)((i < 2 ? h0[i * 4 + 0] : h1[(i - 2) * 4 + 0])));
      float xb = bf2f((unsigned short)((i < 2 ? h0[i * 4 + 1] : h1[(i - 2) * 4 + 1])));
      float xc = bf2f((unsigned short)((i < 2 ? h0[i * 4 + 2] : h1[(i - 2) * 4 + 2])));
      float xd = bf2f((unsigned short)((i < 2 ? h0[i * 4 + 3] : h1[(i - 2) * 4 + 3])));
      fv[4 * i + 0] = xa + scale * d4.x;
      fv[4 * i + 1] = xb + scale * d4.y;
      fv[4 * i + 2] = xc + scale * d4.z;
      fv[4 * i + 3] = xd + scale * d4.w;
      ssum += fv[4 * i + 0] + fv[4 * i + 1] + fv[4 * i + 2] + fv[4 * i + 3];
      ssq += fv[4 * i + 0] * fv[4 * i + 0] + fv[4 * i + 1] * fv[4 * i + 1]
           + fv[4 * i + 2] * fv[4 * i + 2] + fv[4 * i + 3] * fv[4 * i + 3];
    }
#pragma unroll
    for (int m = 1; m < 64; m <<= 1) {
      ssum += __shfl_xor(ssum, m);
      ssq += __shfl_xor(ssq, m);
    }
    float mu = ssum * (1.0f / 1024.0f);
    float var = ssq * (1.0f / 1024.0f) - mu * mu;
    float inv = rsqrtf(var + 1e-5f);
    float* orow = out + (size_t)(m0 + row) * DM + lane * 16;
    const float* gp = gma + lane * 16;
    const float* bp2 = bta + lane * 16;
#pragma unroll
    for (int i = 0; i < 4; ++i) {
      float4 g4 = *(const float4*)(gp + 4 * i);
      float4 b4 = *(const float4*)(bp2 + 4 * i);
      float4 o;
      o.x = (fv[4 * i + 0] - mu) * inv * g4.x + b4.x;
      o.y = (fv[4 * i + 1] - mu) * inv * g4.y + b4.y;
      o.z = (fv[4 * i + 2] - mu) * inv * g4.z + b4.z;
      o.w = (fv[4 * i + 3] - mu) * inv * g4.w + b4.w;
      *(float4*)(orow + 4 * i) = o;
    }
  }
}

extern "C" void kernel_launch(void* const* d_in, const int* in_sizes, int n_in,
                              void* d_out, int out_size, void* d_ws, size_t ws_size,
                              hipStream_t stream) {
  const float* x      = (const float*)d_in[0];
  const float* sigraw = (const float*)d_in[1];
  const float* knots  = (const float*)d_in[2];
  const float* temp   = (const float*)d_in[3];
  const float* cw1    = (const float*)d_in[4];
  const float* cb1    = (const float*)d_in[5];
  const float* cw2    = (const float*)d_in[6];
  const float* cb2    = (const float*)d_in[7];
  const float* sw1    = (const float*)d_in[8];
  const float* sb1    = (const float*)d_in[9];
  const float* sw2    = (const float*)d_in[10];
  const float* sb2    = (const float*)d_in[11];
  const float* dirs   = (const float*)d_in[12];
  const float* gma    = (const float*)d_in[13];
  const float* bta    = (const float*)d_in[14];
  const float* oscale = (const float*)d_in[15];
  float* out = (float*)d_out;

  unsigned short* wsB = (unsigned short*)d_ws;   // 1,572,864 B

  hipLaunchKernelGGL(prep_kernel, dim3(32), dim3(256), 0, stream,
                     sigraw, cw1, wsB);
  hipLaunchKernelGGL(fused_kernel, dim3(N_TOK / 32), dim3(512), 0, stream,
                     x, wsB, cb1, cw2, cb2, knots, temp,
                     sw1, sb1, sw2, sb2, dirs, gma, bta, oscale, out);
}

// Round 7
// 176.124 us; speedup vs baseline: 1.2038x; 1.0460x over previous
//
#include <hip/hip_runtime.h>
#include <hip/hip_bf16.h>
#include <cmath>

// Problem constants
#define N_TOK 16384   // 4*4096
#define DM    1024
#define CH    256
#define SGRID 16
#define NTP   24      // padded n-tiles in ws (21 real: 16 W1 + 5 score)
// wsB layout (ushort): [((kk*24 + nt)*64 + lane)*8 + j] = bf16(B[k][n])
//   k = kk*32 + (lane>>4)*8 + j, n = nt*16 + (lane&15), kk in [0,32)

typedef __attribute__((ext_vector_type(8))) short short8;
typedef __attribute__((ext_vector_type(4))) float floatx4;

__device__ __forceinline__ unsigned short f2bf(float f) {
  union { float f; unsigned int u; } v; v.f = f;
  unsigned int r = v.u + 0x7FFFu + ((v.u >> 16) & 1u);  // RNE
  return (unsigned short)(r >> 16);
}

__device__ __forceinline__ short8 cvt8(float4 u, float4 v) {
  union { short8 s; __hip_bfloat162 h[4]; } r;
  r.h[0] = __float22bfloat162_rn(make_float2(u.x, u.y));
  r.h[1] = __float22bfloat162_rn(make_float2(u.z, u.w));
  r.h[2] = __float22bfloat162_rn(make_float2(v.x, v.y));
  r.h[3] = __float22bfloat162_rn(make_float2(v.z, v.w));
  return r.s;
}

__device__ __forceinline__ float bf2f(unsigned short b) {
  union { unsigned int u; float f; } v; v.u = ((unsigned int)b) << 16; return v.f;
}

__device__ __forceinline__ float calibrate(float s, const float* __restrict__ kn, float temp_eff) {
  float nrm = 1.0f / (1.0f + expf(-s / temp_eff));
  float idxf = nrm * 7.0f;
  int il = (int)idxf; if (il > 6) il = 6;
  float tt = idxf - (float)il;
  float lo = kn[il], hi = kn[il + 1];
  return lo + tt * (hi - lo);
}

// ---------------- K0: prep swizzled B (grid 32 = one block per kk) ----------------
__global__ __launch_bounds__(256) void prep_kernel(
    const float* __restrict__ sig_raw, const float* __restrict__ w1,
    unsigned short* __restrict__ wsB) {
  __shared__ float Wt[32][260];
  __shared__ float St[64][33];
  int kk = blockIdx.x, tid = threadIdx.x;
  {
    int r = tid >> 3, c0 = (tid & 7) * 32;
    const float* src = w1 + (size_t)(kk * 32 + r) * CH + c0;
#pragma unroll
    for (int i = 0; i < 8; ++i)
      *(float4*)(&Wt[r][c0 + 4 * i]) = *(const float4*)(src + 4 * i);
  }
  {
    int t = tid >> 2, c0 = (tid & 3) * 8;
    const float* src = sig_raw + (size_t)t * DM + kk * 32 + c0;
#pragma unroll
    for (int i = 0; i < 8; ++i) {
      float rr = src[i];
      St[t][c0 + i] = (rr > 0.3f) ? 1.f : ((rr < -0.3f) ? -1.f : 0.f);
    }
  }
  __syncthreads();
#pragma unroll
  for (int i = 0; i < 4; ++i) {
    int idx = i * 256 + tid;
    int nt = idx >> 6, lane = idx & 63;
    int q = lane >> 4, l = lane & 15;
    short8 v;
#pragma unroll
    for (int j = 0; j < 8; ++j) v[j] = (short)f2bf(Wt[q * 8 + j][nt * 16 + l]);
    *(short8*)(wsB + ((size_t)(kk * NTP + nt) * 64 + lane) * 8) = v;
  }
#pragma unroll
  for (int i = 0; i < 2; ++i) {
    int idx = i * 256 + tid;
    if (idx < 320) {
      int nt = 16 + (idx >> 6), lane = idx & 63;
      int q = lane >> 4, l = lane & 15;
      int n = nt * 16 + l;
      short8 v;
#pragma unroll
      for (int j = 0; j < 8; ++j) {
        int kl = q * 8 + j;
        float val = 0.f;
        if (n < 264) {
          float s = 0.f;
#pragma unroll
          for (int m = 0; m < 8; ++m) s += St[(n - 256) * 8 + m][kl];
          val = (s > 0.f) ? 1.f : ((s < 0.f) ? -1.f : 0.f);
        } else if (n < 328) {
          val = St[n - 264][kl];
        }
        v[j] = (short)f2bf(val);
      }
      *(short8*)(wsB + ((size_t)(kk * NTP + nt) * 64 + lane) * 8) = v;
    }
  }
}

// ---------------- K1: fused GEMM + routing + spline + residual + LN ----------------
// grid 256 (64 tokens/block), 1024 threads (16 waves), 1 block/CU.
// x staged ONCE to LDS (bf16, XOR-swizzled 16B chunks). K-loop barrier-free.
// Wave w: ALL 4 m-tiles x n-tile(s) {w} + {16+w if w<5}. B amortized over 4 m-tiles.

#define LOADK(kk, b0, b1, av)                                               \
  {                                                                         \
    const char* bp = bBase + (size_t)(kk) * (NTP * 1024);                   \
    b0 = *(const short8*)(bp);                                              \
    if (wave < 5) b1 = *(const short8*)(bp + 16384);                        \
    unsigned cpos = ((unsigned)((kk) * 4 + quad) ^ sw) << 3;                \
    _Pragma("unroll") for (int mt = 0; mt < 4; ++mt)                        \
        av[mt] = *(const short8*)(Xsh + mt * 16384 + arow + cpos);          \
  }

#define COMPUTE(b0, b1, av)                                                 \
  {                                                                         \
    _Pragma("unroll") for (int mt = 0; mt < 4; ++mt)                        \
      acc0[mt] = __builtin_amdgcn_mfma_f32_16x16x32_bf16(av[mt], b0, acc0[mt], 0, 0, 0); \
    if (wave < 5) {                                                         \
      _Pragma("unroll") for (int mt = 0; mt < 4; ++mt)                      \
        acc1[mt] = __builtin_amdgcn_mfma_f32_16x16x32_bf16(av[mt], b1, acc1[mt], 0, 0, 0); \
    }                                                                       \
  }

__global__ __launch_bounds__(1024, 4) void fused_kernel(
    const float* __restrict__ x, const unsigned short* __restrict__ wsB,
    const float* __restrict__ b1v, const float* __restrict__ w2,
    const float* __restrict__ b2, const float* __restrict__ knots,
    const float* __restrict__ temperature, const float* __restrict__ sw1,
    const float* __restrict__ sb1, const float* __restrict__ sw2,
    const float* __restrict__ sb2, const float* __restrict__ dirs,
    const float* __restrict__ gma, const float* __restrict__ bta,
    const float* __restrict__ oscale, float* __restrict__ out) {
  __shared__ unsigned short Xsh[64 * 1024];   // 128 KB: row*1024 + (chunk^(row&7))*8
  __shared__ float Ssc[64][73];               // 18.7 KB scores
  __shared__ float Psh[16][64][2];            // 8 KB comp partials
  __shared__ float ScaleS[64];
  __shared__ int   TidxS[64];

  int tid = threadIdx.x;
  int wave = tid >> 6, lane = tid & 63, quad = lane >> 4, l15 = lane & 15;
  int m0 = blockIdx.x * 64;

  // ---- stage x -> Xsh (bf16, swizzled), fully coalesced ----
  {
    const float* base = x + (size_t)m0 * DM;
#pragma unroll
    for (int i2 = 0; i2 < 8; ++i2) {
      int cg = tid + 1024 * i2;               // chunk 0..8191
      float4 p = *(const float4*)(base + cg * 8);
      float4 q = *(const float4*)(base + cg * 8 + 4);
      int row = cg >> 7, cir = cg & 127;
      int pos = cir ^ (row & 7);
      *(short8*)(Xsh + row * 1024 + pos * 8) = cvt8(p, q);
    }
  }
  __syncthreads();

  floatx4 acc0[4], acc1[4];
#pragma unroll
  for (int mt = 0; mt < 4; ++mt) {
    acc0[mt] = (floatx4){0.f, 0.f, 0.f, 0.f};
    acc1[mt] = (floatx4){0.f, 0.f, 0.f, 0.f};
  }

  // B base for this wave's primary n-tile (nt = wave); secondary at +16*1024 B
  const char* bBase = (const char*)wsB + wave * 1024 + lane * 16;
  int arow = l15 * 1024;                      // ushort offset within m-tile slab
  unsigned sw = (unsigned)(l15 & 7);

  short8 bA0, bA1, bB0, bB1, aA[4], aB_[4];
  LOADK(0, bA0, bA1, aA);
#pragma unroll 1
  for (int kk = 0; kk < 30; kk += 2) {
    LOADK(kk + 1, bB0, bB1, aB_);
    COMPUTE(bA0, bA1, aA);
    LOADK(kk + 2, bA0, bA1, aA);
    COMPUTE(bB0, bB1, aB_);
  }
  LOADK(31, bB0, bB1, aB_);
  COMPUTE(bA0, bA1, aA);
  COMPUTE(bB0, bB1, aB_);

  // ---- scores -> LDS (waves 0..4, secondary tile 16+w -> sc = w*16 + l15) ----
  if (wave < 5) {
    int sc = wave * 16 + l15;
    if (sc < 72) {
#pragma unroll
      for (int mt = 0; mt < 4; ++mt)
#pragma unroll
        for (int r = 0; r < 4; ++r)
          Ssc[mt * 16 + quad * 4 + r][sc] = acc1[mt][r];
    }
  }

  // ---- comp partials: wave w owns W1 cols w*16..w*16+15 ----
  {
    int col = wave * 16 + l15;
    float b1c = b1v[col], w20 = w2[2 * col], w21 = w2[2 * col + 1];
    float p0[4], p1[4];
#pragma unroll
    for (int mt = 0; mt < 4; ++mt) { p0[mt] = 0.f; p1[mt] = 0.f; }
#pragma unroll
    for (int mt = 0; mt < 4; ++mt)
#pragma unroll
      for (int r = 0; r < 4; ++r) {
        float hh = acc0[mt][r] + b1c;
        hh = 0.5f * hh * (1.0f + erff(hh * 0.7071067811865475f));
        // accumulate per (mt,r) -> later reduce over l15; keep per-r in regs
        // store into p-arrays indexed by r via rotation below
        if (r == 0) { p0[mt] += hh * w20; p1[mt] += hh * w21; }
        else if (r == 1) { p0[mt] = p0[mt]; p1[mt] = p1[mt]; p0[mt] += 0.f; p1[mt] += 0.f;
          // handled in full array below
        }
      }
    // The above partial trick is wrong for r>0; do it straightforwardly:
  }
  // straightforward comp partials (4 mt x 4 r)
  {
    int col = wave * 16 + l15;
    float b1c = b1v[col], w20 = w2[2 * col], w21 = w2[2 * col + 1];
    float q0[4][4], q1[4][4];
#pragma unroll
    for (int mt = 0; mt < 4; ++mt)
#pragma unroll
      for (int r = 0; r < 4; ++r) {
        float hh = acc0[mt][r] + b1c;
        hh = 0.5f * hh * (1.0f + erff(hh * 0.7071067811865475f));
        q0[mt][r] = hh * w20;
        q1[mt][r] = hh * w21;
      }
#pragma unroll
    for (int m = 1; m < 16; m <<= 1)
#pragma unroll
      for (int mt = 0; mt < 4; ++mt)
#pragma unroll
        for (int r = 0; r < 4; ++r) {
          q0[mt][r] += __shfl_xor(q0[mt][r], m);
          q1[mt][r] += __shfl_xor(q1[mt][r], m);
        }
    if (l15 == 0) {
#pragma unroll
      for (int mt = 0; mt < 4; ++mt)
#pragma unroll
        for (int r = 0; r < 4; ++r) {
          Psh[wave][mt * 16 + quad * 4 + r][0] = q0[mt][r];
          Psh[wave][mt * 16 + quad * 4 + r][1] = q1[mt][r];
        }
    }
  }
  __syncthreads();

  // ---- per-token: comp combine + routing + spline ----
  if (tid < 64) {
    int row = tid;
    float s0 = b2[0], s1 = b2[1];
#pragma unroll
    for (int j = 0; j < 16; ++j) {
      s0 += Psh[j][row][0];
      s1 += Psh[j][row][1];
    }
    float c0 = tanhf(s0), c1 = tanhf(s1);

    float temp_eff = temperature[0] + 1e-6f;
    int cid = 0; float best = -1e30f;
#pragma unroll
    for (int c = 0; c < 8; ++c) {
      float g = calibrate(Ssc[row][c], knots, temp_eff);
      if (g > best) { best = g; cid = c; }
    }
    int lidx = 0; best = -1e30f;
#pragma unroll
    for (int j = 0; j < 8; ++j) {
      float g = calibrate(Ssc[row][8 + cid * 8 + j], knots, temp_eff);
      if (g > best) { best = g; lidx = j; }
    }
    int t = cid * 8 + lidx;

    float mag = sb2[t];
#pragma unroll
    for (int g2 = 0; g2 < SGRID; ++g2) {
      float hv = c0 * sw1[t * 32 + g2] + c1 * sw1[t * 32 + 16 + g2] + sb1[t * 16 + g2];
      hv = fmaxf(hv, 0.f);
      mag += hv * sw2[t * 16 + g2];
    }
    ScaleS[row] = mag * oscale[0];
    TidxS[row] = t;
  }
  __syncthreads();

  // ---- residual + LN: wave w -> rows w*4..w*4+3; x from Xsh (bf16) ----
#pragma unroll 1
  for (int rr = 0; rr < 4; ++rr) {
    int row = wave * 4 + rr;
    int r7 = row & 7;
    float scale = ScaleS[row];
    const float* dr = dirs + (size_t)TidxS[row] * DM + lane * 16;
    const unsigned short* xrow = Xsh + row * 1024;
    short8 h0 = *(const short8*)(xrow + (unsigned)((2 * lane) ^ r7) * 8);
    short8 h1 = *(const short8*)(xrow + (unsigned)((2 * lane + 1) ^ r7) * 8);
    float fv[16];
    float ssum = 0.f, ssq = 0.f;
#pragma unroll
    for (int i = 0; i < 4; ++i) {
      float4 d4 = *(const float4*)(dr + 4 * i);
      float xa = bf2f((unsigned short)((i < 2 ? h0[i * 4 + 0] : h1[(i - 2) * 4 + 0])));
      float xb = bf2f((unsigned short)((i < 2 ? h0[i * 4 + 1] : h1[(i - 2) * 4 + 1])));
      float xc = bf2f((unsigned short)((i < 2 ? h0[i * 4 + 2] : h1[(i - 2) * 4 + 2])));
      float xd = bf2f((unsigned short)((i < 2 ? h0[i * 4 + 3] : h1[(i - 2) * 4 + 3])));
      fv[4 * i + 0] = xa + scale * d4.x;
      fv[4 * i + 1] = xb + scale * d4.y;
      fv[4 * i + 2] = xc + scale * d4.z;
      fv[4 * i + 3] = xd + scale * d4.w;
      ssum += fv[4 * i + 0] + fv[4 * i + 1] + fv[4 * i + 2] + fv[4 * i + 3];
      ssq += fv[4 * i + 0] * fv[4 * i + 0] + fv[4 * i + 1] * fv[4 * i + 1]
           + fv[4 * i + 2] * fv[4 * i + 2] + fv[4 * i + 3] * fv[4 * i + 3];
    }
#pragma unroll
    for (int m = 1; m < 64; m <<= 1) {
      ssum += __shfl_xor(ssum, m);
      ssq += __shfl_xor(ssq, m);
    }
    float mu = ssum * (1.0f / 1024.0f);
    float var = ssq * (1.0f / 1024.0f) - mu * mu;
    float inv = rsqrtf(var + 1e-5f);
    float* orow = out + (size_t)(m0 + row) * DM + lane * 16;
    const float* gp = gma + lane * 16;
    const float* bp2 = bta + lane * 16;
#pragma unroll
    for (int i = 0; i < 4; ++i) {
      float4 g4 = *(const float4*)(gp + 4 * i);
      float4 b4 = *(const float4*)(bp2 + 4 * i);
      float4 o;
      o.x = (fv[4 * i + 0] - mu) * inv * g4.x + b4.x;
      o.y = (fv[4 * i + 1] - mu) * inv * g4.y + b4.y;
      o.z = (fv[4 * i + 2] - mu) * inv * g4.z + b4.z;
      o.w = (fv[4 * i + 3] - mu) * inv * g4.w + b4.w;
      *(float4*)(orow + 4 * i) = o;
    }
  }
}

extern "C" void kernel_launch(void* const* d_in, const int* in_sizes, int n_in,
                              void* d_out, int out_size, void* d_ws, size_t ws_size,
                              hipStream_t stream) {
  const float* x      = (const float*)d_in[0];
  const float* sigraw = (const float*)d_in[1];
  const float* knots  = (const float*)d_in[2];
  const float* temp   = (const float*)d_in[3];
  const float* cw1    = (const float*)d_in[4];
  const float* cb1    = (const float*)d_in[5];
  const float* cw2    = (const float*)d_in[6];
  const float* cb2    = (const float*)d_in[7];
  const float* sw1    = (const float*)d_in[8];
  const float* sb1    = (const float*)d_in[9];
  const float* sw2    = (const float*)d_in[10];
  const float* sb2    = (const float*)d_in[11];
  const float* dirs   = (const float*)d_in[12];
  const float* gma    = (const float*)d_in[13];
  const float* bta    = (const float*)d_in[14];
  const float* oscale = (const float*)d_in[15];
  float* out = (float*)d_out;

  unsigned short* wsB = (unsigned short*)d_ws;   // 1,572,864 B

  hipLaunchKernelGGL(prep_kernel, dim3(32), dim3(256), 0, stream,
                     sigraw, cw1, wsB);
  hipLaunchKernelGGL(fused_kernel, dim3(N_TOK / 64), dim3(1024), 0, stream,
                     x, wsB, cb1, cw2, cb2, knots, temp,
                     sw1, sb1, sw2, sb2, dirs, gma, bta, oscale, out);
}